// Round 1
// baseline (409.634 us; speedup 1.0000x reference)
//
#include <hip/hip_runtime.h>
#include <hip/hip_bf16.h>

// ---- problem constants ----
#define L_IN     220500
#define PADK     1024
#define LP       222548            // L_IN + 2048 (reflect-padded length)
#define LPP      222560            // LP rounded up to multiple of 16 elems (16B-aligned rows)
#define BATCH    32
#define NFFT     2048
#define HOPSZ    512
#define T_FR     431               // (LP - NFFT)/HOP + 1
#define F_BINS   1025
#define M_TOT    (BATCH * T_FR)    // 13792
#define N_TOT    (2 * F_BINS)      // 2050
#define K_TOT    NFFT              // 2048

typedef short  short8  __attribute__((ext_vector_type(8)));
typedef float  floatx4 __attribute__((ext_vector_type(4)));

__device__ __forceinline__ void glds16(const void* g, void* l) {
    __builtin_amdgcn_global_load_lds(
        (const __attribute__((address_space(1))) void*)g,
        (__attribute__((address_space(3))) void*)l, 16, 0, 0);
}

// ---- pass 1a: reflect-pad + convert x -> bf16, row stride LPP ----
__global__ void k_prep_x(const float* __restrict__ x, __hip_bfloat16* __restrict__ xp) {
    int i = blockIdx.x * 256 + threadIdx.x;   // index within padded row
    int b = blockIdx.y;
    if (i >= LP) return;
    int j = i - PADK;
    if (j < 0) j = -j;
    if (j >= L_IN) j = 2 * L_IN - 2 - j;
    xp[(size_t)b * LPP + i] = __float2bfloat16(x[(size_t)b * L_IN + j]);
}

// ---- pass 1b: concat wcos|wsin -> bf16 [2050][2048] ----
__global__ void k_prep_w(const float* __restrict__ wcos, const float* __restrict__ wsin,
                         __hip_bfloat16* __restrict__ wb) {
    int i = blockIdx.x * 256 + threadIdx.x;
    if (i >= N_TOT * K_TOT) return;
    int n = i >> 11;          // /2048
    int k = i & (K_TOT - 1);
    float v = (n < F_BINS) ? wcos[(size_t)n * K_TOT + k]
                           : wsin[(size_t)(n - F_BINS) * K_TOT + k];
    wb[i] = __float2bfloat16(v);
}

// ---- pass 2: bf16 MFMA GEMM (m97 structure), fused STFT epilogue ----
__global__ __launch_bounds__(256, 2) void k_gemm(
    const __hip_bfloat16* __restrict__ xp,
    const __hip_bfloat16* __restrict__ wb,
    float* __restrict__ out) {

    __shared__ short As[128 * 64];   // [row][k], 128B rows, no padding (global_load_lds layout)
    __shared__ short Bs[128 * 64];   // [n][k]

    const int tid  = threadIdx.x;
    const int wave = tid >> 6;
    const int lane = tid & 63;
    const int waveM = wave >> 1;     // 2x2 wave grid, each wave 64x64
    const int waveN = wave & 1;
    const int bm = blockIdx.x;       // 108 M-tiles
    const int bn = blockIdx.y;       // 17  N-tiles

    // per-lane row bases for staging (8 rows per wave-issue, 4 issues each for A and B)
    long arow[4], brow[4];
    for (int q = 0; q < 4; ++q) {
        int row = wave * 32 + q * 8 + (lane >> 3);
        int m = bm * 128 + row; if (m > M_TOT - 1) m = M_TOT - 1;   // clamp; masked in epilogue
        int b = m / T_FR, t = m - b * T_FR;
        arow[q] = (long)b * LPP + (long)t * HOPSZ;
        int n = bn * 128 + row; if (n > N_TOT - 1) n = N_TOT - 1;
        brow[q] = (long)n * K_TOT;
    }
    const int colo = (lane & 7) * 8;  // element offset within the 64-elem row slice

    floatx4 acc[4][4] = {};

    for (int k0 = 0; k0 < K_TOT; k0 += 64) {
        for (int q = 0; q < 4; ++q)
            glds16(xp + arow[q] + k0 + colo, (char*)As + (wave * 32 + q * 8) * 128);
        for (int q = 0; q < 4; ++q)
            glds16(wb + brow[q] + k0 + colo, (char*)Bs + (wave * 32 + q * 8) * 128);
        __syncthreads();   // compiler drains vmcnt(0) before s_barrier

        for (int kk = 0; kk < 2; ++kk) {
            const int ko = kk * 32 + (lane >> 4) * 8;
            short8 a[4], b[4];
            for (int i = 0; i < 4; ++i)
                a[i] = *(const short8*)&As[(waveM * 64 + i * 16 + (lane & 15)) * 64 + ko];
            for (int j = 0; j < 4; ++j)
                b[j] = *(const short8*)&Bs[(waveN * 64 + j * 16 + (lane & 15)) * 64 + ko];
            for (int i = 0; i < 4; ++i)
                for (int j = 0; j < 4; ++j)
                    acc[i][j] = __builtin_amdgcn_mfma_f32_16x16x32_bf16(a[i], b[j], acc[i][j], 0, 0, 0);
        }
        __syncthreads();
    }

    // epilogue: C[m][n] -> out[b, k, t, c] with imag negated
    for (int i = 0; i < 4; ++i) {
        int mbase = bm * 128 + waveM * 64 + i * 16 + ((lane >> 4) << 2);
        for (int r = 0; r < 4; ++r) {
            int m = mbase + r;
            if (m >= M_TOT) continue;
            int b = m / T_FR, t = m - b * T_FR;
            for (int j = 0; j < 4; ++j) {
                int n = bn * 128 + waveN * 64 + j * 16 + (lane & 15);
                if (n >= N_TOT) continue;
                float v = acc[i][j][r];
                int k, c;
                if (n < F_BINS) { k = n; c = 0; }
                else            { k = n - F_BINS; c = 1; v = -v; }
                out[(((long)b * F_BINS + k) * T_FR + t) * 2 + c] = v;
            }
        }
    }
}

extern "C" void kernel_launch(void* const* d_in, const int* in_sizes, int n_in,
                              void* d_out, int out_size, void* d_ws, size_t ws_size,
                              hipStream_t stream) {
    const float* x    = (const float*)d_in[0];
    const float* wcos = (const float*)d_in[1];
    const float* wsin = (const float*)d_in[2];
    float* out = (float*)d_out;

    // ws layout: xp_bf16 [32][LPP] then w_bf16 [2050][2048]  (~22.6 MB total)
    __hip_bfloat16* xp = (__hip_bfloat16*)d_ws;
    __hip_bfloat16* wb = (__hip_bfloat16*)((char*)d_ws + (size_t)BATCH * LPP * sizeof(__hip_bfloat16));

    k_prep_x<<<dim3((LP + 255) / 256, BATCH), 256, 0, stream>>>(x, xp);
    k_prep_w<<<(N_TOT * K_TOT + 255) / 256, 256, 0, stream>>>(wcos, wsin, wb);

    const int mt = (M_TOT + 127) / 128;   // 108
    const int nt = (N_TOT + 127) / 128;   // 17
    k_gemm<<<dim3(mt, nt), 256, 0, stream>>>(xp, wb, out);
}

// Round 2
// 311.594 us; speedup vs baseline: 1.3146x; 1.3146x over previous
//
#include <hip/hip_runtime.h>
#include <hip/hip_bf16.h>

// ---- problem constants ----
#define L_IN     220500
#define PADK     1024
#define LP       222548            // L_IN + 2048 (reflect-padded length)
#define LPP      222560            // LP rounded up to multiple of 16 elems (16B-aligned rows)
#define BATCH    32
#define NFFT     2048
#define HOPSZ    512
#define T_FR     431               // (LP - NFFT)/HOP + 1
#define F_BINS   1025
#define M_TOT    (BATCH * T_FR)    // 13792 (frames)
#define N_TOT    (2 * F_BINS)      // 2050  (interleaved n' = 2k + c)
#define K_TOT    NFFT              // 2048

typedef short  short8  __attribute__((ext_vector_type(8)));
typedef float  floatx4 __attribute__((ext_vector_type(4)));

__device__ __forceinline__ void glds16(const void* g, void* l) {
    __builtin_amdgcn_global_load_lds(
        (const __attribute__((address_space(1))) void*)g,
        (__attribute__((address_space(3))) void*)l, 16, 0, 0);
}

// ---- pass 1a: reflect-pad + convert x -> bf16, row stride LPP ----
__global__ void k_prep_x(const float* __restrict__ x, __hip_bfloat16* __restrict__ xp) {
    int i = blockIdx.x * 256 + threadIdx.x;   // index within padded row
    int b = blockIdx.y;
    if (i >= LP) return;
    int j = i - PADK;
    if (j < 0) j = -j;
    if (j >= L_IN) j = 2 * L_IN - 2 - j;
    xp[(size_t)b * LPP + i] = __float2bfloat16(x[(size_t)b * L_IN + j]);
}

// ---- pass 1b: interleave wcos/wsin -> bf16 [2050][2048], row n' = 2k + c ----
__global__ void k_prep_w(const float* __restrict__ wcos, const float* __restrict__ wsin,
                         __hip_bfloat16* __restrict__ wb) {
    int i = blockIdx.x * 256 + threadIdx.x;
    if (i >= N_TOT * K_TOT) return;
    int np = i >> 11;         // row n' = 2k + c
    int k  = i & (K_TOT - 1);
    int kf = np >> 1;
    float v = (np & 1) ? wsin[(size_t)kf * K_TOT + k]
                       : wcos[(size_t)kf * K_TOT + k];
    wb[i] = __float2bfloat16(v);
}

// ---- pass 2: bf16 MFMA GEMM computing C^T, fused coalesced STFT epilogue ----
__global__ __launch_bounds__(256, 2) void k_gemm(
    const __hip_bfloat16* __restrict__ xp,
    const __hip_bfloat16* __restrict__ wb,
    float* __restrict__ out) {

    __shared__ short As[128 * 64];   // x frames   [row=m][k], 128B rows, unpadded (glds layout)
    __shared__ short Bs[128 * 64];   // weights    [row=n'][k]

    const int tid  = threadIdx.x;
    const int wave = tid >> 6;
    const int lane = tid & 63;
    const int quad = lane >> 4;
    const int waveM = wave >> 1;     // 2x2 wave grid, each wave 64(m) x 64(n')
    const int waveN = wave & 1;
    const int bm = blockIdx.x;       // 108 M-tiles
    const int bn = blockIdx.y;       // 17  N-tiles

    // per-lane row bases for staging (8 rows per issue, 4 issues each for A and B)
    long arow[4], brow[4];
    for (int q = 0; q < 4; ++q) {
        int row = wave * 32 + q * 8 + (lane >> 3);
        int m = bm * 128 + row; if (m > M_TOT - 1) m = M_TOT - 1;   // clamp; masked at store
        int b = m / T_FR, t = m - b * T_FR;
        arow[q] = (long)b * LPP + (long)t * HOPSZ;
        int n = bn * 128 + row; if (n > N_TOT - 1) n = N_TOT - 1;
        brow[q] = (long)n * K_TOT;
    }
    const int colo = (lane & 7) * 8;  // element offset within the 64-elem row slice

    floatx4 acc[4][4] = {};           // acc[i = n'-block][j = m-block]

    for (int k0 = 0; k0 < K_TOT; k0 += 64) {
        for (int q = 0; q < 4; ++q)
            glds16(xp + arow[q] + k0 + colo, (char*)As + (wave * 32 + q * 8) * 128);
        for (int q = 0; q < 4; ++q)
            glds16(wb + brow[q] + k0 + colo, (char*)Bs + (wave * 32 + q * 8) * 128);
        __syncthreads();   // compiler drains vmcnt(0) before s_barrier

        for (int kk = 0; kk < 2; ++kk) {
            const int ko = kk * 32 + quad * 8;
            short8 wf[4], xf[4];
            for (int i = 0; i < 4; ++i)
                wf[i] = *(const short8*)&Bs[(waveN * 64 + i * 16 + (lane & 15)) * 64 + ko];
            for (int j = 0; j < 4; ++j)
                xf[j] = *(const short8*)&As[(waveM * 64 + j * 16 + (lane & 15)) * 64 + ko];
            for (int i = 0; i < 4; ++i)
                for (int j = 0; j < 4; ++j)
                    // C^T: D rows = n' (first operand), D cols = m (second operand)
                    acc[i][j] = __builtin_amdgcn_mfma_f32_16x16x32_bf16(wf[i], xf[j], acc[i][j], 0, 0, 0);
        }
        __syncthreads();
    }

    // epilogue: lane&15 = m (consecutive t), regs = consecutive n' = (k, re/im) pairs
    // out2[(b*1025 + k)*431 + t] = {real, -imag}  -> 8B/lane, 128B contiguous per quad
    float2* __restrict__ out2 = (float2*)out;
    const int mcol = bm * 128 + waveM * 64 + (lane & 15);
    for (int j = 0; j < 4; ++j) {
        int m = mcol + j * 16;
        if (m >= M_TOT) continue;
        int b = m / T_FR, t = m - b * T_FR;
        long tbase = (long)b * F_BINS * T_FR + t;
        for (int i = 0; i < 4; ++i) {
            int nbase = bn * 128 + waveN * 64 + i * 16 + quad * 4;
            for (int p = 0; p < 2; ++p) {
                int np = nbase + 2 * p;
                if (np >= N_TOT) continue;
                int k = np >> 1;
                float2 v;
                v.x =  acc[i][j][2 * p];        // c=0: wcos conv = real
                v.y = -acc[i][j][2 * p + 1];    // c=1: wsin conv, negated
                out2[tbase + (long)k * T_FR] = v;
            }
        }
    }
}

extern "C" void kernel_launch(void* const* d_in, const int* in_sizes, int n_in,
                              void* d_out, int out_size, void* d_ws, size_t ws_size,
                              hipStream_t stream) {
    const float* x    = (const float*)d_in[0];
    const float* wcos = (const float*)d_in[1];
    const float* wsin = (const float*)d_in[2];
    float* out = (float*)d_out;

    // ws layout: xp_bf16 [32][LPP] then w_bf16 [2050][2048]  (~22.6 MB total)
    __hip_bfloat16* xp = (__hip_bfloat16*)d_ws;
    __hip_bfloat16* wb = (__hip_bfloat16*)((char*)d_ws + (size_t)BATCH * LPP * sizeof(__hip_bfloat16));

    k_prep_x<<<dim3((LP + 255) / 256, BATCH), 256, 0, stream>>>(x, xp);
    k_prep_w<<<(N_TOT * K_TOT + 255) / 256, 256, 0, stream>>>(wcos, wsin, wb);

    const int mt = (M_TOT + 127) / 128;   // 108
    const int nt = (N_TOT + 127) / 128;   // 17
    k_gemm<<<dim3(mt, nt), 256, 0, stream>>>(xp, wb, out);
}

// Round 3
// 289.501 us; speedup vs baseline: 1.4150x; 1.0763x over previous
//
#include <hip/hip_runtime.h>
#include <hip/hip_bf16.h>

// ---- problem constants ----
#define L_IN     220500
#define PADK     1024
#define LP       222548            // L_IN + 2048 (reflect-padded length)
#define LPP      222560            // LP rounded up to multiple of 16 elems (16B-aligned rows)
#define BATCH    32
#define NFFT     2048
#define HOPSZ    512
#define T_FR     431               // (LP - NFFT)/HOP + 1
#define F_BINS   1025
#define M_TOT    (BATCH * T_FR)    // 13792 (frames)
#define N_TOT    (2 * F_BINS)      // 2050  (interleaved n' = 2k + c)
#define K_TOT    NFFT              // 2048

typedef short  short8  __attribute__((ext_vector_type(8)));
typedef float  floatx4 __attribute__((ext_vector_type(4)));

__device__ __forceinline__ void glds16(const void* g, void* l) {
    __builtin_amdgcn_global_load_lds(
        (const __attribute__((address_space(1))) void*)g,
        (__attribute__((address_space(3))) void*)l, 16, 0, 0);
}

// ---- pass 1a: reflect-pad + convert x -> bf16, row stride LPP ----
__global__ void k_prep_x(const float* __restrict__ x, __hip_bfloat16* __restrict__ xp) {
    int i = blockIdx.x * 256 + threadIdx.x;   // index within padded row
    int b = blockIdx.y;
    if (i >= LP) return;
    int j = i - PADK;
    if (j < 0) j = -j;
    if (j >= L_IN) j = 2 * L_IN - 2 - j;
    xp[(size_t)b * LPP + i] = __float2bfloat16(x[(size_t)b * L_IN + j]);
}

// ---- pass 1b: interleave wcos/wsin -> bf16 [2050][2048], row n' = 2k + c ----
__global__ void k_prep_w(const float* __restrict__ wcos, const float* __restrict__ wsin,
                         __hip_bfloat16* __restrict__ wb) {
    int i = blockIdx.x * 256 + threadIdx.x;
    if (i >= N_TOT * K_TOT) return;
    int np = i >> 11;         // row n' = 2k + c
    int k  = i & (K_TOT - 1);
    int kf = np >> 1;
    float v = (np & 1) ? wsin[(size_t)kf * K_TOT + k]
                       : wcos[(size_t)kf * K_TOT + k];
    wb[i] = __float2bfloat16(v);
}

// ---- pass 2: bf16 MFMA GEMM computing C^T, XOR-swizzled LDS, fused epilogue ----
// LDS layout: LDS[row][c] = global[row][c ^ (row&7)]   (c = 16B chunk index, 8 per row)
// Staging lane l loads global chunk (l&7)^(l>>3); read of chunk G from row R uses
// LDS chunk G^(R&7)  ->  quad lanes hit all 32 banks at 2 lanes/bank (conflict-free).
__global__ __launch_bounds__(256, 2) void k_gemm(
    const __hip_bfloat16* __restrict__ xp,
    const __hip_bfloat16* __restrict__ wb,
    float* __restrict__ out) {

    __shared__ short As[128 * 64];   // x frames [row=m][k-chunk swizzled]
    __shared__ short Bs[128 * 64];   // weights  [row=n'][k-chunk swizzled]

    const int tid  = threadIdx.x;
    const int wave = tid >> 6;
    const int lane = tid & 63;
    const int quad = lane >> 4;
    const int waveM = wave >> 1;     // 2x2 wave grid, each wave 64(m) x 64(n')
    const int waveN = wave & 1;
    const int bm = blockIdx.x;       // 108 M-tiles
    const int bn = blockIdx.y;       // 17  N-tiles

    // per-lane row bases for staging (8 rows per issue, 4 issues each for A and B)
    long arow[4], brow[4];
    for (int q = 0; q < 4; ++q) {
        int row = wave * 32 + q * 8 + (lane >> 3);
        int m = bm * 128 + row; if (m > M_TOT - 1) m = M_TOT - 1;   // clamp; masked at store
        int b = m / T_FR, t = m - b * T_FR;
        arow[q] = (long)b * LPP + (long)t * HOPSZ;
        int n = bn * 128 + row; if (n > N_TOT - 1) n = N_TOT - 1;
        brow[q] = (long)n * K_TOT;
    }
    // swizzled source chunk: lane at LDS chunk (lane&7) of row (lane>>3) loads
    // global chunk (lane&7) ^ (lane>>3)   [row within its 8-group == row&7]
    const int colo = (((lane & 7) ^ (lane >> 3)) * 8);

    floatx4 acc[4][4] = {};           // acc[i = n'-block][j = m-block]

    for (int k0 = 0; k0 < K_TOT; k0 += 64) {
        for (int q = 0; q < 4; ++q)
            glds16(xp + arow[q] + k0 + colo, (char*)As + (wave * 32 + q * 8) * 128);
        for (int q = 0; q < 4; ++q)
            glds16(wb + brow[q] + k0 + colo, (char*)Bs + (wave * 32 + q * 8) * 128);
        __syncthreads();   // compiler drains vmcnt(0) before s_barrier

        for (int kk = 0; kk < 2; ++kk) {
            const int gchunk = kk * 4 + quad;          // global 16B-chunk index (ko>>3)
            short8 wf[4], xf[4];
            for (int i = 0; i < 4; ++i) {
                int R = waveN * 64 + i * 16 + (lane & 15);
                wf[i] = *(const short8*)&Bs[R * 64 + ((gchunk ^ (R & 7)) << 3)];
            }
            for (int j = 0; j < 4; ++j) {
                int R = waveM * 64 + j * 16 + (lane & 15);
                xf[j] = *(const short8*)&As[R * 64 + ((gchunk ^ (R & 7)) << 3)];
            }
            for (int i = 0; i < 4; ++i)
                for (int j = 0; j < 4; ++j)
                    // C^T: D rows = n' (first operand), D cols = m (second operand)
                    acc[i][j] = __builtin_amdgcn_mfma_f32_16x16x32_bf16(wf[i], xf[j], acc[i][j], 0, 0, 0);
        }
        __syncthreads();
    }

    // epilogue: lane&15 = m (consecutive t), regs = consecutive n' = (k, re/im) pairs
    // out2[(b*1025 + k)*431 + t] = {real, -imag}  -> 8B/lane, 128B contiguous per quad
    float2* __restrict__ out2 = (float2*)out;
    const int mcol = bm * 128 + waveM * 64 + (lane & 15);
    for (int j = 0; j < 4; ++j) {
        int m = mcol + j * 16;
        if (m >= M_TOT) continue;
        int b = m / T_FR, t = m - b * T_FR;
        long tbase = (long)b * F_BINS * T_FR + t;
        for (int i = 0; i < 4; ++i) {
            int nbase = bn * 128 + waveN * 64 + i * 16 + quad * 4;
            for (int p = 0; p < 2; ++p) {
                int np = nbase + 2 * p;
                if (np >= N_TOT) continue;
                int k = np >> 1;
                float2 v;
                v.x =  acc[i][j][2 * p];        // c=0: wcos conv = real
                v.y = -acc[i][j][2 * p + 1];    // c=1: wsin conv, negated
                out2[tbase + (long)k * T_FR] = v;
            }
        }
    }
}

extern "C" void kernel_launch(void* const* d_in, const int* in_sizes, int n_in,
                              void* d_out, int out_size, void* d_ws, size_t ws_size,
                              hipStream_t stream) {
    const float* x    = (const float*)d_in[0];
    const float* wcos = (const float*)d_in[1];
    const float* wsin = (const float*)d_in[2];
    float* out = (float*)d_out;

    // ws layout: xp_bf16 [32][LPP] then w_bf16 [2050][2048]  (~22.6 MB total)
    __hip_bfloat16* xp = (__hip_bfloat16*)d_ws;
    __hip_bfloat16* wb = (__hip_bfloat16*)((char*)d_ws + (size_t)BATCH * LPP * sizeof(__hip_bfloat16));

    k_prep_x<<<dim3((LP + 255) / 256, BATCH), 256, 0, stream>>>(x, xp);
    k_prep_w<<<(N_TOT * K_TOT + 255) / 256, 256, 0, stream>>>(wcos, wsin, wb);

    const int mt = (M_TOT + 127) / 128;   // 108
    const int nt = (N_TOT + 127) / 128;   // 17
    k_gemm<<<dim3(mt, nt), 256, 0, stream>>>(xp, wb, out);
}